// Round 12
// baseline (539.324 us; speedup 1.0000x reference)
//
#include <hip/hip_runtime.h>

#define B_ 4
#define T_ 2048
#define C_ 2048
#define H_ 16
#define N1_ 6144
#define M_ 8192
#define SCL2_ 0.12751744f   // (1/sqrt(128)) * log2(e)  -> softmax in exp2 domain

typedef unsigned short u16;
typedef __bf16 bf16x8 __attribute__((ext_vector_type(8)));
typedef float f32x4 __attribute__((ext_vector_type(4)));
typedef float f32x16 __attribute__((ext_vector_type(16)));

__device__ __forceinline__ u16 f2bf(float f) {
  union { float f; unsigned u; } v; v.f = f;
  return (u16)((v.u + 0x7fffu + ((v.u >> 16) & 1u)) >> 16);
}

// async global->LDS, 16B per lane. LDS dest must be wave-uniform base + lane*16.
__device__ __forceinline__ void gld16(const void* g, void* l) {
  __builtin_amdgcn_global_load_lds(
      (__attribute__((address_space(1))) unsigned int*)(unsigned long long)g,
      (__attribute__((address_space(3))) unsigned int*)(unsigned)(unsigned long long)l,
      16, 0, 0);
}

// fused prep: bf16 casts of x, w_attn, w_proj + RoPE trig table, one launch.
__global__ void k_prep(const float* __restrict__ x, const float* __restrict__ wa,
                       const float* __restrict__ wp, u16* __restrict__ xb,
                       u16* __restrict__ wab, u16* __restrict__ wpb,
                       float2* __restrict__ trig) {
  int bid = blockIdx.x, tid = threadIdx.x;
  if (bid < 32768) {
    const float* src; u16* dst; int i;
    if (bid < 16384)      { src = x;  dst = xb;  i = bid * 256 + tid; }
    else if (bid < 28672) { src = wa; dst = wab; i = (bid - 16384) * 256 + tid; }
    else                  { src = wp; dst = wpb; i = (bid - 28672) * 256 + tid; }
    float4 v = reinterpret_cast<const float4*>(src)[i];
    ushort4 o;
    o.x = f2bf(v.x); o.y = f2bf(v.y); o.z = f2bf(v.z); o.w = f2bf(v.w);
    reinterpret_cast<ushort4*>(dst)[i] = o;
  } else {
    int idx = (bid - 32768) * 256 + tid;
    int t = idx >> 6, i = idx & 63;
    float theta = __expf(-(float)i * 0.14391156831212787f);
    float s, c;
    sincosf((float)t * theta, &s, &c);
    trig[idx] = make_float2(c, s);
  }
}

// ---- 256x256 8-phase GEMM (round-5 schedule) + fragment-major LDS ----------
// C[M][N] = A[M][2048] * Bt[N][2048]^T ; BM=BN=256 BK=64; 8 waves (2M x 4N);
// per-wave 128x64; 2 LDS buffers; 8 phases / 2 K-tiles; single barrier per
// phase (top); counted vmcnt(4)@P4, vmcnt(6)@P8; T5 setprio.
// LDS layout is FRAGMENT-MAJOR: each MFMA read-unit (rowblk of 16 rows x one
// k-slot-quad) is a contiguous 1KB block, lane-ordered -> every ds_read_b128
// is lane-contiguous (8 perfect 128B beats, peak LDS rate, no swizzle needed).
// Unit u = rowblk*2 + ks; chunk = u*64 + lane; lane l -> (row=rowblk*16+(l&15),
// slot=ks*4+(l>>4)) — identical operand semantics to the old unswizzled map.

#define STAGE_H(BUF, AB, HALF, KT, GSH)                                          \
  {                                                                              \
    _Pragma("unroll") for (int q = 0; q < 2; ++q) {                              \
      int c = tid + q * 512;                                                     \
      int u = c >> 6;                                                            \
      int ks = u & 1;                                                            \
      int rbl = u >> 1;                                                          \
      int rowblk = (rbl & ((1 << ((GSH)-4)) - 1)) + ((HALF) << ((GSH)-4)) +      \
                   ((rbl >> ((GSH)-4)) << ((GSH)-3));                            \
      int row = rowblk * 16 + (c & 15);                                          \
      int slot = ks * 4 + ((c >> 4) & 3);                                        \
      gld16(((AB) ? Bg : Ag) + (long)row * 2048 + (long)(KT) * 64 + slot * 8,    \
            (char*)&lds[BUF][AB][((rowblk * 2 + ks) * 64 + (c & 63)) * 8]);      \
    }                                                                            \
  }

#define PHASE(BUF, MH, NH, RDA, RDB, STAGE_CODE, WAIT_CODE)                      \
  {                                                                              \
    __builtin_amdgcn_s_barrier();                                                \
    __builtin_amdgcn_sched_barrier(0);                                           \
    if (RDA) {                                                                   \
      _Pragma("unroll") for (int fr = 0; fr < 4; ++fr)                           \
        _Pragma("unroll") for (int ks = 0; ks < 2; ++ks)                         \
          aCur[fr][ks] = *reinterpret_cast<const bf16x8*>(                       \
              &lds[BUF][0][(((wm * 8 + (MH) * 4 + fr) * 2 + ks) * 64 + lane) *   \
                           8]);                                                  \
    }                                                                            \
    if (RDB) {                                                                   \
      _Pragma("unroll") for (int fc = 0; fc < 2; ++fc)                           \
        _Pragma("unroll") for (int ks = 0; ks < 2; ++ks)                         \
          bKp[NH][fc][ks] = *reinterpret_cast<const bf16x8*>(                    \
              &lds[BUF][1][(((wn * 4 + (NH) * 2 + fc) * 2 + ks) * 64 + lane) *   \
                           8]);                                                  \
    }                                                                            \
    STAGE_CODE;                                                                  \
    __builtin_amdgcn_s_setprio(1);                                               \
    _Pragma("unroll") for (int fr = 0; fr < 4; ++fr)                             \
      _Pragma("unroll") for (int fc = 0; fc < 2; ++fc)                           \
        _Pragma("unroll") for (int ks = 0; ks < 2; ++ks)                         \
          acc[(MH) * 4 + fr][(NH) * 2 + fc] =                                    \
              __builtin_amdgcn_mfma_f32_16x16x32_bf16(                           \
                  aCur[fr][ks], bKp[NH][fc][ks],                                 \
                  acc[(MH) * 4 + fr][(NH) * 2 + fc], 0, 0, 0);                   \
    __builtin_amdgcn_s_setprio(0);                                               \
    WAIT_CODE;                                                                   \
  }

#define VMW(N) asm volatile("s_waitcnt vmcnt(" #N ")" ::: "memory")

template <int EPI>
__global__ __launch_bounds__(512, 2) void k_gemm8(
    const u16* __restrict__ A, const u16* __restrict__ Bt,
    float* __restrict__ Cf,
    u16* __restrict__ qh, u16* __restrict__ kh, u16* __restrict__ vt,
    const float2* __restrict__ trig, int nbx, int cpx) {
  __shared__ alignas(16) u16 lds[2][2][256 * 64];
  const int tid = threadIdx.x;
  const int lane = tid & 63;
  const int w = tid >> 6;
  const int wm = w >> 2;          // 2 M-waves
  const int wn = w & 3;           // 4 N-waves
  const int l15 = lane & 15, lq = lane >> 4;

  const int id = (int)blockIdx.x;
  const int swz = (id & 7) * cpx + (id >> 3);   // bijective (grid % 8 == 0)
  const int bx = swz % nbx, by = swz / nbx;
  const long rowBase = (long)by * 256;
  const long colBase = (long)bx * 256;
  const u16* Ag = A + rowBase * 2048;
  const u16* Bg = Bt + colBase * 2048;

  const f32x4 z4 = {0.f, 0.f, 0.f, 0.f};
  f32x4 acc[8][4];
#pragma unroll
  for (int m = 0; m < 8; ++m)
#pragma unroll
    for (int n = 0; n < 4; ++n) acc[m][n] = z4;
  bf16x8 aCur[4][2], bKp[2][2][2];

  // prologue: tile0 -> buf0 (all 4 halves), tile1 -> buf1 halves A0,B0
  STAGE_H(0, 0, 0, 0, 6); STAGE_H(0, 1, 0, 0, 5);
  STAGE_H(0, 0, 1, 0, 6); STAGE_H(0, 1, 1, 0, 5);
  STAGE_H(1, 0, 0, 1, 6); STAGE_H(1, 1, 0, 1, 5);
  VMW(6);

#pragma unroll 1
  for (int i = 0; i < 16; ++i) {
    const int t1 = 2 * i + 1, t2 = 2 * i + 2, t3 = 2 * i + 3;
    const bool st = (i < 15);
    PHASE(0, 0, 0, 1, 1, STAGE_H(1, 0, 1, t1, 6), );
    PHASE(0, 0, 1, 0, 1, STAGE_H(1, 1, 1, t1, 5), );
    PHASE(0, 1, 0, 1, 0, if (st) STAGE_H(0, 0, 0, t2, 6), );
    PHASE(0, 1, 1, 0, 0, if (st) STAGE_H(0, 1, 0, t2, 5),
          if (st) { VMW(4); } else { VMW(0); });
    PHASE(1, 0, 0, 1, 1, if (st) STAGE_H(0, 0, 1, t2, 6), );
    PHASE(1, 0, 1, 0, 1, if (st) STAGE_H(0, 1, 1, t2, 5), );
    PHASE(1, 1, 0, 1, 0, if (st) STAGE_H(1, 0, 0, t3, 6), );
    PHASE(1, 1, 1, 0, 0, if (st) STAGE_H(1, 1, 0, t3, 5),
          if (st) { VMW(6); });
  }

  if (EPI == 0) {
#pragma unroll
    for (int fr = 0; fr < 8; ++fr) {
      long row0 = rowBase + wm * 128 + fr * 16 + lq * 4;
#pragma unroll
      for (int fc = 0; fc < 4; ++fc) {
        long col = colBase + wn * 64 + fc * 16 + l15;
#pragma unroll
        for (int j = 0; j < 4; ++j)
          Cf[(row0 + j) * 2048 + col] = acc[fr][fc][j];
      }
    }
  } else {
    const int sec = (int)(colBase >> 11);          // 0=q 1=k 2=v
#pragma unroll
    for (int fr = 0; fr < 8; ++fr) {
      int row0 = (int)rowBase + wm * 128 + fr * 16 + lq * 4;
      int b = row0 >> 11;
      int t0 = row0 & (T_ - 1);
#pragma unroll
      for (int fc = 0; fc < 4; ++fc) {
        int cc = (int)colBase + wn * 64 + fc * 16;
        int hh = (cc >> 7) & 15;
        int dd = (cc & 127) + l15;
        long bh = (long)b * H_ + hh;
        if (sec < 2) {
          u16* dst = sec ? kh : qh;
#pragma unroll
          for (int j = 0; j < 4; ++j) {
            float v = acc[fr][fc][j];
            float vp = __shfl_xor(v, 1);
            float2 cs = trig[(t0 + j) * 64 + (dd >> 1)];
            float r = (dd & 1) ? (vp * cs.y + v * cs.x) : (v * cs.x - vp * cs.y);
            dst[(bh * T_ + t0 + j) * 128 + dd] = f2bf(r);
          }
        } else {
          ushort4 pk;
          pk.x = f2bf(acc[fr][fc][0]); pk.y = f2bf(acc[fr][fc][1]);
          pk.z = f2bf(acc[fr][fc][2]); pk.w = f2bf(acc[fr][fc][3]);
          *reinterpret_cast<ushort4*>(&vt[(bh * 128 + dd) * T_ + t0]) = pk;
        }
      }
    }
  }
}

// pack 8 f32 P-values (S^T reg layout) into one PV A-fragment via cvt_pk + permlane32_swap
#define PACK_SLOT(dst, P, base)                                                       \
  {                                                                                   \
    unsigned ua, ub, uc, ud;                                                          \
    asm("v_cvt_pk_bf16_f32 %0, %1, %2" : "=v"(ua) : "v"(P[base + 0]), "v"(P[base + 1])); \
    asm("v_cvt_pk_bf16_f32 %0, %1, %2" : "=v"(ub) : "v"(P[base + 4]), "v"(P[base + 5])); \
    asm("v_permlane32_swap_b32 %0, %1" : "+v"(ua), "+v"(ub));                         \
    asm("v_cvt_pk_bf16_f32 %0, %1, %2" : "=v"(uc) : "v"(P[base + 2]), "v"(P[base + 3])); \
    asm("v_cvt_pk_bf16_f32 %0, %1, %2" : "=v"(ud) : "v"(P[base + 6]), "v"(P[base + 7])); \
    asm("v_permlane32_swap_b32 %0, %1" : "+v"(uc), "+v"(ud));                         \
    union { unsigned u[4]; bf16x8 v; } tt;                                            \
    tt.u[0] = ua; tt.u[1] = uc; tt.u[2] = ub; tt.u[3] = ud;                           \
    dst = tt.v;                                                                       \
  }

// flash attention, swapped-QK^T 32x32 structure; exp2 softmax + defer-max.
__global__ __launch_bounds__(256, 2) void k_attn(
    const u16* __restrict__ qh, const u16* __restrict__ kh,
    const u16* __restrict__ vt, u16* __restrict__ ym) {
  __shared__ alignas(16) u16 lK[2][64 * 128];
  __shared__ alignas(16) u16 lV[2][128 * 64];
  const int tid = threadIdx.x;
  const int lane = tid & 63;
  const int w = tid >> 6;
  const int l31 = lane & 31;
  const int hi = lane >> 5;
  const int swzK = (l31 & 15) << 4;
  const int swzV = (l31 & 7) << 4;
  const int id = (int)blockIdx.x;
  const int pr = id >> 6;
  const int bh = ((id & 7) << 3) | ((id >> 3) & 7);
  const int b = bh >> 4, hh = bh & 15;
  const u16* Kbase = kh + (long)bh * T_ * 128;
  const u16* Vbase = vt + (long)bh * 128 * T_;
  const u16* Qbase = qh + (long)bh * T_ * 128;

  auto stage = [&](int bi, int t0) {
#pragma unroll
    for (int i = 0; i < 4; ++i) {
      int c = tid + i * 256;
      int rK = c >> 4;
      int lbK = ((c & 15) ^ (rK & 15)) << 4;
      gld16(Kbase + (long)(t0 + rK) * 128 + (lbK >> 1), (char*)(&lK[bi][0]) + c * 16);
      int dV = c >> 3;
      int lbV = ((c & 7) << 4) ^ ((dV & 7) << 4);
      gld16(Vbase + (long)dV * T_ + t0 + (lbV >> 1), (char*)(&lV[bi][0]) + c * 16);
    }
  };

#pragma unroll 1
  for (int half = 0; half < 2; ++half) {
    const int p = half ? 15 - pr : pr;
    const int NT = 2 * (p + 1);
    const int qw = p * 128 + w * 32;
    const int ntw = (qw + 95) >> 6;

    bf16x8 qF[8];
    {
      const u16* qrow = Qbase + (long)(qw + l31) * 128 + hi * 8;
#pragma unroll
      for (int s = 0; s < 8; ++s)
        qF[s] = *reinterpret_cast<const bf16x8*>(qrow + s * 16);
    }

    f32x16 oA[4];
#pragma unroll
    for (int n = 0; n < 4; ++n)
#pragma unroll
      for (int r = 0; r < 16; ++r) oA[n][r] = 0.f;
    float mR = -1e30f, lR = 0.f;

    stage(0, 0);
    __syncthreads();
    int cur = 0;
#pragma unroll 1
    for (int jt = 0; jt < NT; ++jt) {
      if (jt + 1 < NT) stage(cur ^ 1, (jt + 1) * 64);
      if (jt < ntw) {
        const int t0 = jt * 64;
        const char* Kc = (const char*)(&lK[cur][0]);
        const char* Vc = (const char*)(&lV[cur][0]);
        f32x16 s0, s1;
#pragma unroll
        for (int r = 0; r < 16; ++r) { s0[r] = 0.f; s1[r] = 0.f; }
        __builtin_amdgcn_s_setprio(1);
#pragma unroll
        for (int s = 0; s < 8; ++s) {
          int cb = (s * 32 + hi * 16) ^ swzK;
          bf16x8 k0 = *reinterpret_cast<const bf16x8*>(Kc + l31 * 256 + cb);
          bf16x8 k1 = *reinterpret_cast<const bf16x8*>(Kc + (32 + l31) * 256 + cb);
          s0 = __builtin_amdgcn_mfma_f32_32x32x16_bf16(k0, qF[s], s0, 0, 0, 0);
          s1 = __builtin_amdgcn_mfma_f32_32x32x16_bf16(k1, qF[s], s1, 0, 0, 0);
        }
        __builtin_amdgcn_s_setprio(0);

        float f0[16], f1[16];
#pragma unroll
        for (int r = 0; r < 16; ++r) { f0[r] = s0[r] * SCL2_; f1[r] = s1[r] * SCL2_; }
        if (jt == ntw - 1) {
          const int qa = qw + l31;
#pragma unroll
          for (int r = 0; r < 16; ++r) {
            int kv = t0 + (r & 3) + 8 * (r >> 2) + 4 * hi;
            if (kv > qa) f0[r] = -1e30f;
            if (kv + 32 > qa) f1[r] = -1e30f;
          }
        }
        float mt = fmaxf(f0[0], f1[0]);
#pragma unroll
        for (int r = 1; r < 16; ++r) mt = fmaxf(mt, fmaxf(f0[r], f1[r]));
        mt = fmaxf(mt, __shfl_xor(mt, 32));
        // T13 defer-max: only rescale when some row's max grew by > 8 (2^8 headroom)
        if (!__all(mt - mR <= 8.0f)) {
          float mN = fmaxf(mR, mt);
          float al = exp2f(mR - mN);
          lR *= al;
          float aR[16];
#pragma unroll
          for (int r = 0; r < 16; ++r)
            aR[r] = __shfl(al, (r & 3) + 8 * (r >> 2) + 4 * hi);
#pragma unroll
          for (int n = 0; n < 4; ++n)
#pragma unroll
            for (int r = 0; r < 16; ++r) oA[n][r] *= aR[r];
          mR = mN;
        }
        float rs = 0.f;
#pragma unroll
        for (int r = 0; r < 16; ++r) {
          f0[r] = exp2f(f0[r] - mR);
          f1[r] = exp2f(f1[r] - mR);
          rs += f0[r] + f1[r];
        }
        rs += __shfl_xor(rs, 32);
        lR += rs;

        bf16x8 paF[4];
        PACK_SLOT(paF[0], f0, 0);
        PACK_SLOT(paF[1], f0, 8);
        PACK_SLOT(paF[2], f1, 0);
        PACK_SLOT(paF[3], f1, 8);

        __builtin_amdgcn_s_setprio(1);
#pragma unroll
        for (int n = 0; n < 4; ++n) {
          const char* vrow = Vc + (n * 32 + l31) * 128;
#pragma unroll
          for (int ks = 0; ks < 4; ++ks) {
            bf16x8 bV = *reinterpret_cast<const bf16x8*>(vrow + ((ks * 32 + hi * 16) ^ swzV));
            oA[n] = __builtin_amdgcn_mfma_f32_32x32x16_bf16(paF[ks], bV, oA[n], 0, 0, 0);
          }
        }
        __builtin_amdgcn_s_setprio(0);
      }
      __syncthreads();
      cur ^= 1;
    }

    float li = 1.f / lR;
    float liR[16];
#pragma unroll
    for (int r = 0; r < 16; ++r)
      liR[r] = __shfl(li, (r & 3) + 8 * (r >> 2) + 4 * hi);
    u16* yrow = ym + ((long)b * T_ + qw) * C_ + hh * 128 + l31;
#pragma unroll
    for (int n = 0; n < 4; ++n)
#pragma unroll
      for (int r = 0; r < 16; ++r) {
        int cr = (r & 3) + 8 * (r >> 2) + 4 * hi;
        yrow[(long)cr * C_ + n * 32] = f2bf(oA[n][r] * liR[r]);
      }
  }
}

extern "C" void kernel_launch(void* const* d_in, const int* in_sizes, int n_in,
                              void* d_out, int out_size, void* d_ws, size_t ws_size,
                              hipStream_t stream) {
  (void)in_sizes; (void)n_in; (void)out_size; (void)ws_size;
  const float* x = (const float*)d_in[0];
  const float* wa = (const float*)d_in[1];
  const float* wp = (const float*)d_in[2];
  float* out = (float*)d_out;
  char* ws = (char*)d_ws;

  size_t off = 0;
  auto alloc = [&](size_t bytes) -> char* {
    char* p = ws + off;
    off += (bytes + 255) & ~(size_t)255;
    return p;
  };
  u16* xb  = (u16*)alloc((size_t)M_ * C_ * 2);    // reused as ym after gemm1
  u16* wab = (u16*)alloc((size_t)N1_ * C_ * 2);
  u16* wpb = (u16*)alloc((size_t)C_ * C_ * 2);
  u16* qh  = (u16*)alloc((size_t)64 * T_ * 128 * 2);
  u16* kh  = (u16*)alloc((size_t)64 * T_ * 128 * 2);
  u16* vt  = (u16*)alloc((size_t)64 * 128 * T_ * 2);
  float2* trig = (float2*)alloc((size_t)T_ * 64 * 8);
  u16* ym = xb;

  k_prep<<<dim3(33280), 256, 0, stream>>>(x, wa, wp, xb, wab, wpb, trig);
  // GEMM1: M=8192 N=6144 -> 32*24 = 768 blocks (nbx=24, cpx=96)
  k_gemm8<1><<<dim3(768), 512, 0, stream>>>(
      xb, wab, nullptr, qh, kh, vt, trig, 24, 96);
  k_attn<<<dim3(512), 256, 0, stream>>>(qh, kh, vt, ym);
  // GEMM2: M=8192 N=2048 -> 32*8 = 256 blocks (nbx=8, cpx=32)
  k_gemm8<0><<<dim3(256), 512, 0, stream>>>(
      ym, wpb, out, nullptr, nullptr, nullptr, nullptr, 8, 32);
}

// Round 13
// 404.724 us; speedup vs baseline: 1.3326x; 1.3326x over previous
//
#include <hip/hip_runtime.h>

#define B_ 4
#define T_ 2048
#define C_ 2048
#define H_ 16
#define N1_ 6144
#define M_ 8192
#define SCL2_ 0.12751744f   // (1/sqrt(128)) * log2(e)  -> softmax in exp2 domain

typedef unsigned short u16;
typedef __bf16 bf16x8 __attribute__((ext_vector_type(8)));
typedef float f32x4 __attribute__((ext_vector_type(4)));
typedef float f32x16 __attribute__((ext_vector_type(16)));

__device__ __forceinline__ u16 f2bf(float f) {
  union { float f; unsigned u; } v; v.f = f;
  return (u16)((v.u + 0x7fffu + ((v.u >> 16) & 1u)) >> 16);
}

// async global->LDS, 16B per lane. LDS dest must be wave-uniform base + lane*16.
__device__ __forceinline__ void gld16(const void* g, void* l) {
  __builtin_amdgcn_global_load_lds(
      (__attribute__((address_space(1))) unsigned int*)(unsigned long long)g,
      (__attribute__((address_space(3))) unsigned int*)(unsigned)(unsigned long long)l,
      16, 0, 0);
}

// fused prep: bf16 casts of x, w_attn, w_proj + RoPE trig table, one launch.
__global__ void k_prep(const float* __restrict__ x, const float* __restrict__ wa,
                       const float* __restrict__ wp, u16* __restrict__ xb,
                       u16* __restrict__ wab, u16* __restrict__ wpb,
                       float2* __restrict__ trig) {
  int bid = blockIdx.x, tid = threadIdx.x;
  if (bid < 32768) {
    const float* src; u16* dst; int i;
    if (bid < 16384)      { src = x;  dst = xb;  i = bid * 256 + tid; }
    else if (bid < 28672) { src = wa; dst = wab; i = (bid - 16384) * 256 + tid; }
    else                  { src = wp; dst = wpb; i = (bid - 28672) * 256 + tid; }
    float4 v = reinterpret_cast<const float4*>(src)[i];
    ushort4 o;
    o.x = f2bf(v.x); o.y = f2bf(v.y); o.z = f2bf(v.z); o.w = f2bf(v.w);
    reinterpret_cast<ushort4*>(dst)[i] = o;
  } else {
    int idx = (bid - 32768) * 256 + tid;
    int t = idx >> 6, i = idx & 63;
    float theta = __expf(-(float)i * 0.14391156831212787f);
    float s, c;
    sincosf((float)t * theta, &s, &c);
    trig[idx] = make_float2(c, s);
  }
}

// ---- 256x256 8-phase GEMM (round-5/9 schedule, 16x16x32 MFMA) --------------
// C[M][N] = A[M][2048] * Bt[N][2048]^T ; BM=BN=256 BK=64; 8 waves (2M x 4N);
// per-wave 128x64; 2 LDS buffers; 8 phases / 2 K-tiles; single barrier per
// phase (top); counted vmcnt(4)@P4, vmcnt(6)@P8; T2 XOR swizzle; T5 setprio.
// LESSONS PINNED: (r10) 32x32 frag reads bank-conflict 4-way, keep 16x16;
// (r12) global staging source must stay lane-contiguous — swizzle only the
// k-slot within a row; (r6/r7) do not shorten vmcnt distances or restage a
// region in the same barrier window as its reads.

#define STAGE_H(BUF, AB, HALF, KT, GSH)                                          \
  {                                                                              \
    _Pragma("unroll") for (int q = 0; q < 2; ++q) {                              \
      int c = tid + q * 512;                                                     \
      int idx = c >> 3;                                                          \
      int row = (idx & ((1 << (GSH)) - 1)) + ((HALF) << (GSH)) +                 \
                ((idx >> (GSH)) << ((GSH) + 1));                                 \
      gld16(((AB) ? Bg : Ag) + (long)row * 2048 + (long)(KT) * 64 +              \
                (((c & 7) ^ (idx & 7)) << 3),                                    \
            (char*)&lds[BUF][AB][row * 64 + (c & 7) * 8]);                       \
    }                                                                            \
  }

#define PHASE(BUF, MH, NH, RDA, RDB, STAGE_CODE, WAIT_CODE)                      \
  {                                                                              \
    __builtin_amdgcn_s_barrier();                                                \
    __builtin_amdgcn_sched_barrier(0);                                           \
    if (RDA) {                                                                   \
      _Pragma("unroll") for (int fr = 0; fr < 4; ++fr)                           \
        _Pragma("unroll") for (int ks = 0; ks < 2; ++ks)                         \
          aCur[fr][ks] = *reinterpret_cast<const bf16x8*>(                       \
              &lds[BUF][0][(wm * 128 + (MH) * 64 + fr * 16 + l15) * 64 +         \
                           (((ks * 4 + lq) ^ swl) << 3)]);                       \
    }                                                                            \
    if (RDB) {                                                                   \
      _Pragma("unroll") for (int fc = 0; fc < 2; ++fc)                           \
        _Pragma("unroll") for (int ks = 0; ks < 2; ++ks)                         \
          bKp[NH][fc][ks] = *reinterpret_cast<const bf16x8*>(                    \
              &lds[BUF][1][(wn * 64 + (NH) * 32 + fc * 16 + l15) * 64 +          \
                           (((ks * 4 + lq) ^ swl) << 3)]);                       \
    }                                                                            \
    STAGE_CODE;                                                                  \
    __builtin_amdgcn_s_setprio(1);                                               \
    _Pragma("unroll") for (int fr = 0; fr < 4; ++fr)                             \
      _Pragma("unroll") for (int fc = 0; fc < 2; ++fc)                           \
        _Pragma("unroll") for (int ks = 0; ks < 2; ++ks)                         \
          acc[(MH) * 4 + fr][(NH) * 2 + fc] =                                    \
              __builtin_amdgcn_mfma_f32_16x16x32_bf16(                           \
                  aCur[fr][ks], bKp[NH][fc][ks],                                 \
                  acc[(MH) * 4 + fr][(NH) * 2 + fc], 0, 0, 0);                   \
    __builtin_amdgcn_s_setprio(0);                                               \
    WAIT_CODE;                                                                   \
  }

#define VMW(N) asm volatile("s_waitcnt vmcnt(" #N ")" ::: "memory")

template <int EPI>
__global__ __launch_bounds__(512, 2) void k_gemm8(
    const u16* __restrict__ A, const u16* __restrict__ Bt,
    float* __restrict__ Cf,
    u16* __restrict__ qh, u16* __restrict__ kh, u16* __restrict__ vt,
    const float2* __restrict__ trig, int nbx, int cpx) {
  __shared__ alignas(16) u16 lds[2][2][256 * 64];
  const int tid = threadIdx.x;
  const int lane = tid & 63;
  const int w = tid >> 6;
  const int wm = w >> 2;          // 2 M-waves
  const int wn = w & 3;           // 4 N-waves
  const int l15 = lane & 15, lq = lane >> 4;
  const int swl = l15 & 7;

  const int id = (int)blockIdx.x;
  const int swz = (id & 7) * cpx + (id >> 3);   // bijective (grid % 8 == 0)
  const int bx = swz % nbx, by = swz / nbx;
  const long rowBase = (long)by * 256;
  const long colBase = (long)bx * 256;
  const u16* Ag = A + rowBase * 2048;
  const u16* Bg = Bt + colBase * 2048;

  const f32x4 z4 = {0.f, 0.f, 0.f, 0.f};
  f32x4 acc[8][4];
#pragma unroll
  for (int m = 0; m < 8; ++m)
#pragma unroll
    for (int n = 0; n < 4; ++n) acc[m][n] = z4;
  bf16x8 aCur[4][2], bKp[2][2][2];

  // prologue: tile0 -> buf0 (all 4 halves), tile1 -> buf1 halves A0,B0
  STAGE_H(0, 0, 0, 0, 6); STAGE_H(0, 1, 0, 0, 5);
  STAGE_H(0, 0, 1, 0, 6); STAGE_H(0, 1, 1, 0, 5);
  STAGE_H(1, 0, 0, 1, 6); STAGE_H(1, 1, 0, 1, 5);
  VMW(6);

#pragma unroll 1
  for (int i = 0; i < 16; ++i) {
    const int t1 = 2 * i + 1, t2 = 2 * i + 2, t3 = 2 * i + 3;
    const bool st = (i < 15);
    PHASE(0, 0, 0, 1, 1, STAGE_H(1, 0, 1, t1, 6), );
    PHASE(0, 0, 1, 0, 1, STAGE_H(1, 1, 1, t1, 5), );
    PHASE(0, 1, 0, 1, 0, if (st) STAGE_H(0, 0, 0, t2, 6), );
    PHASE(0, 1, 1, 0, 0, if (st) STAGE_H(0, 1, 0, t2, 5),
          if (st) { VMW(4); } else { VMW(0); });
    PHASE(1, 0, 0, 1, 1, if (st) STAGE_H(0, 0, 1, t2, 6), );
    PHASE(1, 0, 1, 0, 1, if (st) STAGE_H(0, 1, 1, t2, 5), );
    PHASE(1, 1, 0, 1, 0, if (st) STAGE_H(1, 0, 0, t3, 6), );
    PHASE(1, 1, 1, 0, 0, if (st) STAGE_H(1, 1, 0, t3, 5),
          if (st) { VMW(6); });
  }

  if (EPI == 0) {
#pragma unroll
    for (int fr = 0; fr < 8; ++fr) {
      long row0 = rowBase + wm * 128 + fr * 16 + lq * 4;
#pragma unroll
      for (int fc = 0; fc < 4; ++fc) {
        long col = colBase + wn * 64 + fc * 16 + l15;
#pragma unroll
        for (int j = 0; j < 4; ++j)
          Cf[(row0 + j) * 2048 + col] = acc[fr][fc][j];
      }
    }
  } else {
    const int sec = (int)(colBase >> 11);          // 0=q 1=k 2=v
#pragma unroll
    for (int fr = 0; fr < 8; ++fr) {
      int row0 = (int)rowBase + wm * 128 + fr * 16 + lq * 4;
      int b = row0 >> 11;
      int t0 = row0 & (T_ - 1);
#pragma unroll
      for (int fc = 0; fc < 4; ++fc) {
        int cc = (int)colBase + wn * 64 + fc * 16;
        int hh = (cc >> 7) & 15;
        int dd = (cc & 127) + l15;
        long bh = (long)b * H_ + hh;
        if (sec < 2) {
          u16* dst = sec ? kh : qh;
#pragma unroll
          for (int j = 0; j < 4; ++j) {
            float v = acc[fr][fc][j];
            float vp = __shfl_xor(v, 1);
            float2 cs = trig[(t0 + j) * 64 + (dd >> 1)];
            float r = (dd & 1) ? (vp * cs.y + v * cs.x) : (v * cs.x - vp * cs.y);
            dst[(bh * T_ + t0 + j) * 128 + dd] = f2bf(r);
          }
        } else {
          ushort4 pk;
          pk.x = f2bf(acc[fr][fc][0]); pk.y = f2bf(acc[fr][fc][1]);
          pk.z = f2bf(acc[fr][fc][2]); pk.w = f2bf(acc[fr][fc][3]);
          *reinterpret_cast<ushort4*>(&vt[(bh * 128 + dd) * T_ + t0]) = pk;
        }
      }
    }
  }
}

// pack 8 f32 P-values (S^T reg layout) into one PV A-fragment via cvt_pk + permlane32_swap
#define PACK_SLOT(dst, P, base)                                                       \
  {                                                                                   \
    unsigned ua, ub, uc, ud;                                                          \
    asm("v_cvt_pk_bf16_f32 %0, %1, %2" : "=v"(ua) : "v"(P[base + 0]), "v"(P[base + 1])); \
    asm("v_cvt_pk_bf16_f32 %0, %1, %2" : "=v"(ub) : "v"(P[base + 4]), "v"(P[base + 5])); \
    asm("v_permlane32_swap_b32 %0, %1" : "+v"(ua), "+v"(ub));                         \
    asm("v_cvt_pk_bf16_f32 %0, %1, %2" : "=v"(uc) : "v"(P[base + 2]), "v"(P[base + 3])); \
    asm("v_cvt_pk_bf16_f32 %0, %1, %2" : "=v"(ud) : "v"(P[base + 6]), "v"(P[base + 7])); \
    asm("v_permlane32_swap_b32 %0, %1" : "+v"(uc), "+v"(ud));                         \
    union { unsigned u[4]; bf16x8 v; } tt;                                            \
    tt.u[0] = ua; tt.u[1] = uc; tt.u[2] = ub; tt.u[3] = ud;                           \
    dst = tt.v;                                                                       \
  }

// flash attention, swapped-QK^T 32x32 structure; exp2-domain softmax + defer-max.
__global__ __launch_bounds__(256, 2) void k_attn(
    const u16* __restrict__ qh, const u16* __restrict__ kh,
    const u16* __restrict__ vt, u16* __restrict__ ym) {
  __shared__ alignas(16) u16 lK[2][64 * 128];
  __shared__ alignas(16) u16 lV[2][128 * 64];
  const int tid = threadIdx.x;
  const int lane = tid & 63;
  const int w = tid >> 6;
  const int l31 = lane & 31;
  const int hi = lane >> 5;
  const int swz = (l31 & 7) << 4;
  const int id = (int)blockIdx.x;
  const int pr = id >> 6;
  const int bh = ((id & 7) << 3) | ((id >> 3) & 7);
  const int b = bh >> 4, hh = bh & 15;
  const u16* Kbase = kh + (long)bh * T_ * 128;
  const u16* Vbase = vt + (long)bh * 128 * T_;
  const u16* Qbase = qh + (long)bh * T_ * 128;

  auto stage = [&](int bi, int t0) {
#pragma unroll
    for (int i = 0; i < 4; ++i) {
      int c = tid + i * 256;
      int rK = c >> 4;
      int lbK = ((c & 15) << 4) ^ ((rK & 7) << 4);
      gld16(Kbase + (long)(t0 + rK) * 128 + (lbK >> 1), (char*)(&lK[bi][0]) + c * 16);
      int dV = c >> 3;
      int lbV = ((c & 7) << 4) ^ ((dV & 7) << 4);
      gld16(Vbase + (long)dV * T_ + t0 + (lbV >> 1), (char*)(&lV[bi][0]) + c * 16);
    }
  };

#pragma unroll 1
  for (int half = 0; half < 2; ++half) {
    const int p = half ? 15 - pr : pr;
    const int NT = 2 * (p + 1);
    const int qw = p * 128 + w * 32;
    const int ntw = (qw + 95) >> 6;

    bf16x8 qF[8];
    {
      const u16* qrow = Qbase + (long)(qw + l31) * 128 + hi * 8;
#pragma unroll
      for (int s = 0; s < 8; ++s)
        qF[s] = *reinterpret_cast<const bf16x8*>(qrow + s * 16);
    }

    f32x16 oA[4];
#pragma unroll
    for (int n = 0; n < 4; ++n)
#pragma unroll
      for (int r = 0; r < 16; ++r) oA[n][r] = 0.f;
    float mR = -1e30f, lR = 0.f;

    stage(0, 0);
    __syncthreads();
    int cur = 0;
#pragma unroll 1
    for (int jt = 0; jt < NT; ++jt) {
      if (jt + 1 < NT) stage(cur ^ 1, (jt + 1) * 64);
      if (jt < ntw) {
        const int t0 = jt * 64;
        const char* Kc = (const char*)(&lK[cur][0]);
        const char* Vc = (const char*)(&lV[cur][0]);
        f32x16 s0, s1;
#pragma unroll
        for (int r = 0; r < 16; ++r) { s0[r] = 0.f; s1[r] = 0.f; }
        __builtin_amdgcn_s_setprio(1);
#pragma unroll
        for (int s = 0; s < 8; ++s) {
          int cb = (s * 32 + hi * 16) ^ swz;
          bf16x8 k0 = *reinterpret_cast<const bf16x8*>(Kc + l31 * 256 + cb);
          bf16x8 k1 = *reinterpret_cast<const bf16x8*>(Kc + (32 + l31) * 256 + cb);
          s0 = __builtin_amdgcn_mfma_f32_32x32x16_bf16(k0, qF[s], s0, 0, 0, 0);
          s1 = __builtin_amdgcn_mfma_f32_32x32x16_bf16(k1, qF[s], s1, 0, 0, 0);
        }
        __builtin_amdgcn_s_setprio(0);

        float f0[16], f1[16];
#pragma unroll
        for (int r = 0; r < 16; ++r) { f0[r] = s0[r] * SCL2_; f1[r] = s1[r] * SCL2_; }
        if (jt == ntw - 1) {
          const int qa = qw + l31;
#pragma unroll
          for (int r = 0; r < 16; ++r) {
            int kv = t0 + (r & 3) + 8 * (r >> 2) + 4 * hi;
            if (kv > qa) f0[r] = -1e30f;
            if (kv + 32 > qa) f1[r] = -1e30f;
          }
        }
        float mt = fmaxf(f0[0], f1[0]);
#pragma unroll
        for (int r = 1; r < 16; ++r) mt = fmaxf(mt, fmaxf(f0[r], f1[r]));
        mt = fmaxf(mt, __shfl_xor(mt, 32));
        // T13 defer-max: only rescale when some row's max grew by > 8 (2^8 headroom)
        if (!__all(mt - mR <= 8.0f)) {
          float mN = fmaxf(mR, mt);
          float al = exp2f(mR - mN);
          lR *= al;
          float aR[16];
#pragma unroll
          for (int r = 0; r < 16; ++r)
            aR[r] = __shfl(al, (r & 3) + 8 * (r >> 2) + 4 * hi);
#pragma unroll
          for (int n = 0; n < 4; ++n)
#pragma unroll
            for (int r = 0; r < 16; ++r) oA[n][r] *= aR[r];
          mR = mN;
        }
        float rs = 0.f;
#pragma unroll
        for (int r = 0; r < 16; ++r) {
          f0[r] = exp2f(f0[r] - mR);
          f1[r] = exp2f(f1[r] - mR);
          rs += f0[r] + f1[r];
        }
        rs += __shfl_xor(rs, 32);
        lR += rs;

        bf16x8 paF[4];
        PACK_SLOT(paF[0], f0, 0);
        PACK_SLOT(paF[1], f0, 8);
        PACK_SLOT(paF[2], f1, 0);
        PACK_SLOT(paF[3], f1, 8);

        __builtin_amdgcn_s_setprio(1);
#pragma unroll
        for (int n = 0; n < 4; ++n) {
          const char* vrow = Vc + (n * 32 + l31) * 128;
#pragma unroll
          for (int ks = 0; ks < 4; ++ks) {
            bf16x8 bV = *reinterpret_cast<const bf16x8*>(vrow + ((ks * 32 + hi * 16) ^ swz));
            oA[n] = __builtin_amdgcn_mfma_f32_32x32x16_bf16(paF[ks], bV, oA[n], 0, 0, 0);
          }
        }
        __builtin_amdgcn_s_setprio(0);
      }
      __syncthreads();
      cur ^= 1;
    }

    float li = 1.f / lR;
    float liR[16];
#pragma unroll
    for (int r = 0; r < 16; ++r)
      liR[r] = __shfl(li, (r & 3) + 8 * (r >> 2) + 4 * hi);
    u16* yrow = ym + ((long)b * T_ + qw) * C_ + hh * 128 + l31;
#pragma unroll
    for (int n = 0; n < 4; ++n)
#pragma unroll
      for (int r = 0; r < 16; ++r) {
        int cr = (r & 3) + 8 * (r >> 2) + 4 * hi;
        yrow[(long)cr * C_ + n * 32] = f2bf(oA[n][r] * liR[r]);
      }
  }
}

extern "C" void kernel_launch(void* const* d_in, const int* in_sizes, int n_in,
                              void* d_out, int out_size, void* d_ws, size_t ws_size,
                              hipStream_t stream) {
  (void)in_sizes; (void)n_in; (void)out_size; (void)ws_size;
  const float* x = (const float*)d_in[0];
  const float* wa = (const float*)d_in[1];
  const float* wp = (const float*)d_in[2];
  float* out = (float*)d_out;
  char* ws = (char*)d_ws;

  size_t off = 0;
  auto alloc = [&](size_t bytes) -> char* {
    char* p = ws + off;
    off += (bytes + 255) & ~(size_t)255;
    return p;
  };
  u16* xb  = (u16*)alloc((size_t)M_ * C_ * 2);    // reused as ym after gemm1
  u16* wab = (u16*)alloc((size_t)N1_ * C_ * 2);
  u16* wpb = (u16*)alloc((size_t)C_ * C_ * 2);
  u16* qh  = (u16*)alloc((size_t)64 * T_ * 128 * 2);
  u16* kh  = (u16*)alloc((size_t)64 * T_ * 128 * 2);
  u16* vt  = (u16*)alloc((size_t)64 * 128 * T_ * 2);
  float2* trig = (float2*)alloc((size_t)T_ * 64 * 8);
  u16* ym = xb;

  k_prep<<<dim3(33280), 256, 0, stream>>>(x, wa, wp, xb, wab, wpb, trig);
  // GEMM1: M=8192 N=6144 -> 32*24 = 768 blocks (nbx=24, cpx=96)
  k_gemm8<1><<<dim3(768), 512, 0, stream>>>(
      xb, wab, nullptr, qh, kh, vt, trig, 24, 96);
  k_attn<<<dim3(512), 256, 0, stream>>>(qh, kh, vt, ym);
  // GEMM2: M=8192 N=2048 -> 32*8 = 256 blocks (nbx=8, cpx=32)
  k_gemm8<0><<<dim3(256), 512, 0, stream>>>(
      ym, wpb, out, nullptr, nullptr, nullptr, nullptr, 8, 32);
}